// Round 23
// baseline (65.605 us; speedup 1.0000x reference)
//
#include <hip/hip_runtime.h>
#include <stdint.h>
#include <stddef.h>

// MultiTaskTrunkNetwork: 3x (Linear+Tanh) [89->64->64->64] + per-task head [64->8]
// Round 23: task-sorted rows INSIDE the fused kernel (head L1-line attack).
//   r22 math byte-identical; rows indirected via task-sorted idx[] so each
//   wave's 32 rows share ~1-2 tasks -> head weight reads go from ~16 distinct
//   64B lines/instr to ~2 (L1-hot 1-2KB working set vs thrashing 51.2KB).
//   Sort chain = r10's histogram/prefix/scatter (proven correct+benign).
//   Output deterministic: each row's value is position-independent.

typedef _Float16 half8 __attribute__((ext_vector_type(8)));
typedef _Float16 half4 __attribute__((ext_vector_type(4)));
typedef _Float16 half2v __attribute__((ext_vector_type(2)));
typedef float    f32x4 __attribute__((ext_vector_type(4)));

constexpr int BN = 262144, INF = 89, HID = 64, OUTF = 8, NTASK = 50;
constexpr int NTHR = 512;     // 8 waves
constexpr int NW   = 8;       // waves per block
constexpr int ROWS = 256;     // rows (of sorted space) per block (32 per wave)
constexpr int HP   = 72;      // LDS h pitch in f16
constexpr int WLF  = 14336;   // frag-ordered weights in f16 (28672 B)

// d_ws layout (bytes)
constexpr int    W0F_OFF  = 0;        // [3kk][4ft][64lane][8] f16 = 12288 B
constexpr int    W1F_OFF  = 12288;    // [2kk][4ft][64lane][8] f16 = 8192 B
constexpr int    W2F_OFF  = 20480;    // [2kk][4ft][64lane][8] f16 = 8192 B
constexpr int    HWT_OFF  = 28672;    // [50][8][64] f16 = 51200 B
constexpr size_t IDX_OFF  = 79872;                       // [B] i32 sorted rows
constexpr size_t HIST_OFF = IDX_OFF + (size_t)BN * 4;    // [64] i32
constexpr size_t BASE_OFF = HIST_OFF + 256;              // [64] i32
constexpr size_t WS_NEED  = BASE_OFF + 256;

__device__ __forceinline__ float fast_tanh(float v) {
    float e = __expf(2.0f * v);
    return 1.0f - 2.0f * __builtin_amdgcn_rcpf(e + 1.0f);
}

__device__ __forceinline__ float dot2acc(half2v a, half2v b, float c) {
#if __has_builtin(__builtin_amdgcn_fdot2)
    return __builtin_amdgcn_fdot2(a, b, c, false);
#else
    return fmaf((float)a[0], (float)b[0], fmaf((float)a[1], (float)b[1], c));
#endif
}

__global__ void prep_kernel(const float* __restrict__ W0, const float* __restrict__ W1,
                            const float* __restrict__ W2, const float* __restrict__ hW,
                            _Float16* __restrict__ ws) {
    const int tid = blockIdx.x * blockDim.x + threadIdx.x;
    const int stride = gridDim.x * blockDim.x;
    _Float16* w0f = ws + W0F_OFF / 2;
    _Float16* w1f = ws + W1F_OFF / 2;
    _Float16* w2f = ws + W2F_OFF / 2;
    _Float16* hwt = ws + HWT_OFF / 2;
    for (int i = tid; i < 3 * 4 * 64 * 8; i += stride) {
        int j = i & 7, l = (i >> 3) & 63, fk = i >> 9;   // fk = kk*4+ft
        int kk = fk >> 2, ft = fk & 3;
        int n = ft * 16 + (l & 15);
        int g = l >> 4;
        bool tail = (kk == 2 && g == 3);
        int k = (tail ? 81 : kk * 32 + g * 8) + j;       // always <= 88
        float wv = W0[k * HID + n];
        if (tail && j < 7) wv = 0.0f;                    // duplicate k: zero weight
        w0f[i] = (_Float16)wv;
    }
    for (int i = tid; i < 2 * 4 * 64 * 8; i += stride) {
        int j = i & 7, l = (i >> 3) & 63, fk = i >> 9;
        int kk = fk >> 2, ft = fk & 3;
        int n = ft * 16 + (l & 15);
        int k = kk * 32 + (l >> 4) * 8 + j;
        w1f[i] = (_Float16)W1[k * HID + n];
        w2f[i] = (_Float16)W2[k * HID + n];
    }
    for (int i = tid; i < NTASK * OUTF * HID; i += stride) {   // hwT[t][o][k]
        int t = i / (OUTF * HID), rem = i % (OUTF * HID);
        int o = rem / HID, k = rem % HID;
        hwt[i] = (_Float16)hW[(size_t)t * (HID * OUTF) + k * OUTF + o];
    }
}

// ---------------- sort chain (r10, proven) ----------------
__global__ void sort_init(int* __restrict__ hist, int* __restrict__ base) {
    int t = threadIdx.x;
    if (t < 64) { hist[t] = 0; base[t] = 0; }
}

__global__ __launch_bounds__(256) void sort_hist(const int* __restrict__ task,
                                                 int* __restrict__ hist) {
    __shared__ int lh[NTASK];
    const int t = threadIdx.x;
    if (t < NTASK) lh[t] = 0;
    __syncthreads();
    const int base = blockIdx.x * 1024;
    #pragma unroll
    for (int k = 0; k < 4; ++k) atomicAdd(&lh[task[base + t + k * 256]], 1);
    __syncthreads();
    if (t < NTASK) atomicAdd(&hist[t], lh[t]);
}

__global__ void sort_prefix(const int* __restrict__ hist, int* __restrict__ base) {
    if (threadIdx.x == 0) {
        int run = 0;
        for (int i = 0; i < NTASK; ++i) { base[i] = run; run += hist[i]; }
    }
}

__global__ __launch_bounds__(256) void sort_scatter(const int* __restrict__ task,
                                                    int* __restrict__ base,
                                                    int* __restrict__ idx) {
    __shared__ int lcnt[NTASK];
    __shared__ int lbase[NTASK];
    const int t = threadIdx.x;
    if (t < NTASK) lcnt[t] = 0;
    __syncthreads();
    const int rbase = blockIdx.x * 1024;
    int tk[4], rank[4];
    #pragma unroll
    for (int k = 0; k < 4; ++k) {
        tk[k] = task[rbase + t + k * 256];
        rank[k] = atomicAdd(&lcnt[tk[k]], 1);
    }
    __syncthreads();
    if (t < NTASK) lbase[t] = atomicAdd(&base[t], lcnt[t]);
    __syncthreads();
    #pragma unroll
    for (int k = 0; k < 4; ++k)
        idx[lbase[tk[k]] + rank[k]] = rbase + t + k * 256;
}

__global__ void idx_identity(int* __restrict__ idx) {   // ws-too-small fallback
    int i = blockIdx.x * blockDim.x + threadIdx.x;
    idx[i] = i;
}

// ---------------- fused kernel (r22 math, idx-indirected rows) ----------------
__global__ __launch_bounds__(NTHR, 4) void mtn_mfma_kernel(
    const float* __restrict__ x,     // [B, 89]
    const int*   __restrict__ task,  // [B]
    const int*   __restrict__ idx,   // [B] task-sorted row indices
    const float* __restrict__ b0, const float* __restrict__ b1,
    const float* __restrict__ b2,
    const float* __restrict__ hB,    // [50, 8] fp32
    const _Float16* __restrict__ ws,
    float* __restrict__ out)         // [B, 8]
{
    __shared__ __align__(16) _Float16 wl[WLF];          // 28672 B: W0F|W1F|W2F
    __shared__ __align__(16) _Float16 hs[NW][32][HP];   // 36864 B, wave-private bands

    const int t = threadIdx.x;
    const int w = t >> 6;            // wave 0..7
    const int l = t & 63;
    const int c = l & 15;            // MFMA col (batch) / A row (feat)
    const int g = l >> 4;            // k-group / D row-group
    const int waveRow = blockIdx.x * ROWS + w * 32;   // base in SORTED space

    const _Float16* hwt = ws + HWT_OFF / 2;

    // ---- stage ALL trunk weights to LDS (coalesced, amortized over 8 waves)
    {
        const float4* src = reinterpret_cast<const float4*>(ws);   // frag block @0
        float4* dst = reinterpret_cast<float4*>(wl);
        #pragma unroll
        for (int i = 0; i < 3; ++i) dst[t + i * NTHR] = src[t + i * NTHR];
        if (t < 1792 - 3 * NTHR) dst[t + 3 * NTHR] = src[t + 3 * NTHR];
    }

    // ---- row indices for trunk (2 per lane) and head (4 per lane): L1-hot 128B
    int rowT[2];
    #pragma unroll
    for (int bt = 0; bt < 2; ++bt)
        rowT[bt] = idx[waveRow + bt * 16 + c];

    // ---- layer-0 B-fragments: direct global->VGPR from sorted rows
    const int k0_2 = (g == 3) ? 81 : 64 + g * 8;     // kk==2 chunk start
    half8 xf[3][2];
    #pragma unroll
    for (int bt = 0; bt < 2; ++bt) {
        const float* xr = x + (size_t)rowT[bt] * INF;
        #pragma unroll
        for (int kk = 0; kk < 3; ++kk) {
            const int k0 = (kk == 2) ? k0_2 : kk * 32 + g * 8;
            float v[8];
            __builtin_memcpy(v, xr + k0, 32);        // in-bounds: k0+8 <= 89
            half8 hb;
            #pragma unroll
            for (int i2 = 0; i2 < 8; ++i2) hb[i2] = (_Float16)v[i2];
            xf[kk][bt] = hb;
        }
    }

    // ---- head row indices + tasks + biases (nearly uniform after sort)
    const int jr = l >> 3, jo = l & 7;
    int   rowH[4], tks[4];
    float hBv[4];
    #pragma unroll
    for (int it = 0; it < 4; ++it)
        rowH[it] = idx[waveRow + it * 8 + jr];
    #pragma unroll
    for (int it = 0; it < 4; ++it)
        tks[it] = task[rowH[it]];
    #pragma unroll
    for (int it = 0; it < 4; ++it)
        hBv[it] = hB[tks[it] * OUTF + jo];

    __syncthreads();   // weights staged; all af reads below hit LDS

    const _Float16* w0l = wl;                 // [3kk][4ft][64][8]
    const _Float16* w1l = wl + W1F_OFF / 2;
    const _Float16* w2l = wl + W2F_OFF / 2;

    f32x4 acc[4][2];   // [feat-tile][batch-tile]

    // ================= layer 0: K=96-equivalent, A frags from LDS =================
    #pragma unroll
    for (int ft = 0; ft < 4; ++ft) {
        f32x4 bv = *(const f32x4*)(b0 + ft * 16 + g * 4);
        acc[ft][0] = bv; acc[ft][1] = bv;
    }
    #pragma unroll
    for (int kk = 0; kk < 3; ++kk)
        #pragma unroll
        for (int ft = 0; ft < 4; ++ft) {
            half8 af = *(const half8*)(w0l + ((kk * 4 + ft) * 64 + l) * 8);  // ds_read_b128
            acc[ft][0] = __builtin_amdgcn_mfma_f32_16x16x32_f16(af, xf[kk][0], acc[ft][0], 0, 0, 0);
            acc[ft][1] = __builtin_amdgcn_mfma_f32_16x16x32_f16(af, xf[kk][1], acc[ft][1], 0, 0, 0);
        }
    #pragma unroll
    for (int ft = 0; ft < 4; ++ft)
        #pragma unroll
        for (int bt = 0; bt < 2; ++bt) {
            half4 hv;
            #pragma unroll
            for (int r = 0; r < 4; ++r) hv[r] = (_Float16)fast_tanh(acc[ft][bt][r]);
            *(half4*)&hs[w][bt * 16 + c][ft * 16 + g * 4] = hv;   // 8B store
        }

    // ================= layers 1,2: K=64, A and B both from LDS =============
    #pragma unroll
    for (int layer = 0; layer < 2; ++layer) {
        const _Float16* WL  = layer ? w2l : w1l;
        const float*    bia = layer ? b2  : b1;
        #pragma unroll
        for (int ft = 0; ft < 4; ++ft) {
            f32x4 bv = *(const f32x4*)(bia + ft * 16 + g * 4);
            acc[ft][0] = bv; acc[ft][1] = bv;
        }
        #pragma unroll
        for (int kk = 0; kk < 2; ++kk) {
            half8 bf[2];
            #pragma unroll
            for (int bt = 0; bt < 2; ++bt)
                bf[bt] = *(const half8*)&hs[w][bt * 16 + c][kk * 32 + g * 8];  // 16B read
            #pragma unroll
            for (int ft = 0; ft < 4; ++ft) {
                half8 af = *(const half8*)(WL + ((kk * 4 + ft) * 64 + l) * 8);
                acc[ft][0] = __builtin_amdgcn_mfma_f32_16x16x32_f16(af, bf[0], acc[ft][0], 0, 0, 0);
                acc[ft][1] = __builtin_amdgcn_mfma_f32_16x16x32_f16(af, bf[1], acc[ft][1], 0, 0, 0);
            }
        }
        #pragma unroll
        for (int ft = 0; ft < 4; ++ft)
            #pragma unroll
            for (int bt = 0; bt < 2; ++bt) {
                half4 hv;
                #pragma unroll
                for (int r = 0; r < 4; ++r) hv[r] = (_Float16)fast_tanh(acc[ft][bt][r]);
                *(half4*)&hs[w][bt * 16 + c][ft * 16 + g * 4] = hv;
            }
    }

    // ================= head: sorted rows -> weights L1-hot =============
    #pragma unroll
    for (int it = 0; it < 4; ++it) {
        const int r = it * 8 + jr;
        const size_t grow = (size_t)rowH[it];
        const int tk = tks[it];
        const _Float16* wp = hwt + (size_t)tk * (OUTF * HID) + jo * 8;  // chunk jo
        const half8 hv = *(const half8*)&hs[w][r][jo * 8];              // 1 read/it

        float p[8];
        #pragma unroll
        for (int o = 0; o < 8; ++o) {
            half8 wv = *(const half8*)(wp + o * HID);   // ~1-2 tasks/wave: L1-hot
            float a = 0.0f;
            #pragma unroll
            for (int pp = 0; pp < 4; ++pp) {
                half2v av = {hv[2 * pp], hv[2 * pp + 1]};
                half2v bv = {wv[2 * pp], wv[2 * pp + 1]};
                a = dot2acc(av, bv, a);
            }
            p[o] = a;
        }
        // transpose-reduce across the 8 jo-lanes (static indices only)
        float t0 = p[0] + __shfl_xor(p[0], 1);
        float t1 = p[1] + __shfl_xor(p[1], 1);
        float t2 = p[2] + __shfl_xor(p[2], 1);
        float t3 = p[3] + __shfl_xor(p[3], 1);
        float t4 = p[4] + __shfl_xor(p[4], 1);
        float t5 = p[5] + __shfl_xor(p[5], 1);
        float t6 = p[6] + __shfl_xor(p[6], 1);
        float t7 = p[7] + __shfl_xor(p[7], 1);
        const bool b0s = (jo & 1) != 0;
        float s0 = b0s ? t1 : t0;
        float s1 = b0s ? t3 : t2;
        float s2 = b0s ? t5 : t4;
        float s3 = b0s ? t7 : t6;
        s0 += __shfl_xor(s0, 2);
        s1 += __shfl_xor(s1, 2);
        s2 += __shfl_xor(s2, 2);
        s3 += __shfl_xor(s3, 2);
        const bool b1s = (jo & 2) != 0;
        float u0 = b1s ? s1 : s0;
        float u1 = b1s ? s3 : s2;
        u0 += __shfl_xor(u0, 4);
        u1 += __shfl_xor(u1, 4);
        float res = ((jo & 4) ? u1 : u0) + hBv[it];
        out[grow * OUTF + jo] = res;    // 8 lanes -> 32B contiguous per row
    }
}

extern "C" void kernel_launch(void* const* d_in, const int* in_sizes, int n_in,
                              void* d_out, int out_size, void* d_ws, size_t ws_size,
                              hipStream_t stream) {
    const float* x    = (const float*)d_in[0];
    const int*   task = (const int*)  d_in[1];
    const float* W0   = (const float*)d_in[2];
    const float* b0   = (const float*)d_in[3];
    const float* W1   = (const float*)d_in[4];
    const float* b1   = (const float*)d_in[5];
    const float* W2   = (const float*)d_in[6];
    const float* b2   = (const float*)d_in[7];
    const float* hW   = (const float*)d_in[8];
    const float* hB   = (const float*)d_in[9];
    float* out = (float*)d_out;
    _Float16* ws = (_Float16*)d_ws;
    char* wsb = (char*)d_ws;
    int* idx = (int*)(wsb + IDX_OFF);

    prep_kernel<<<64, 256, 0, stream>>>(W0, W1, W2, hW, ws);

    if (ws_size >= WS_NEED) {
        int* hist = (int*)(wsb + HIST_OFF);
        int* base = (int*)(wsb + BASE_OFF);
        sort_init   <<<1,   128, 0, stream>>>(hist, base);
        sort_hist   <<<256, 256, 0, stream>>>(task, hist);
        sort_prefix <<<1,    64, 0, stream>>>(hist, base);
        sort_scatter<<<256, 256, 0, stream>>>(task, base, idx);
    } else {
        idx_identity<<<BN / 256, 256, 0, stream>>>(idx);
    }

    mtn_mfma_kernel<<<BN / ROWS, NTHR, 0, stream>>>(x, task, idx, b0, b1, b2,
                                                    hB, ws, out);
}

// Round 24
// 39.723 us; speedup vs baseline: 1.6515x; 1.6515x over previous
//
#include <hip/hip_runtime.h>
#include <stdint.h>
#include <stddef.h>

// MultiTaskTrunkNetwork: 3x (Linear+Tanh) [89->64->64->64] + per-task head [64->8]
// FINAL (round 24) = r22, the measured best (39.77 us), reverting r23's regression.
//   - 8-wave / 512-thr blocks, 32 rows/wave, barrier-free per-wave pipeline
//   - trunk weights (28.7 KB, frag-ordered) staged once per block into LDS:
//     af loads are ds_read_b128 (r21's confirmed L1-line win, -3.7 us)
//   - layer-0 x fragments loaded direct global->VGPR, branchless overlapped
//     tail (k=81..88 chunk + zeroed duplicate weights)
//   - h kept in wave-private LDS bands [8][32][72] (2-way banks, free)
//   - head: lane=output-chunk, transposed f16 head weights, 128B-contiguous
//     reads per row-group, dot2 accumulate, shuffle transpose-reduce,
//     coalesced 64-dword stores (r6's confirmed win, -13 us)
//   Session ledger: wins were all L1-line reductions (r6, r8, r21); ILP/TLP/
//   pipelining/sort levers all falsified or spill-bound (~64-VGPR wall).

typedef _Float16 half8 __attribute__((ext_vector_type(8)));
typedef _Float16 half4 __attribute__((ext_vector_type(4)));
typedef _Float16 half2v __attribute__((ext_vector_type(2)));
typedef float    f32x4 __attribute__((ext_vector_type(4)));

constexpr int BN = 262144, INF = 89, HID = 64, OUTF = 8, NTASK = 50;
constexpr int NTHR = 512;     // 8 waves
constexpr int NW   = 8;       // waves per block
constexpr int ROWS = 256;     // batch rows per block (32 per wave)
constexpr int HP   = 72;      // LDS h pitch in f16 (144 B: 16B-aligned, 2-way banks)
constexpr int WLF  = 14336;   // frag-ordered weights in f16 (28672 B, contiguous)

// d_ws layout (bytes) — fragment-ordered weights (contiguous block of 28672 B)
constexpr int W0F_OFF = 0;        // [3kk][4ft][64lane][8] f16 = 12288 B
constexpr int W1F_OFF = 12288;    // [2kk][4ft][64lane][8] f16 = 8192 B
constexpr int W2F_OFF = 20480;    // [2kk][4ft][64lane][8] f16 = 8192 B
constexpr int HWT_OFF = 28672;    // [50][8][64] f16 (transposed head weights)

__device__ __forceinline__ float fast_tanh(float v) {
    float e = __expf(2.0f * v);
    return 1.0f - 2.0f * __builtin_amdgcn_rcpf(e + 1.0f);
}

__device__ __forceinline__ float dot2acc(half2v a, half2v b, float c) {
#if __has_builtin(__builtin_amdgcn_fdot2)
    return __builtin_amdgcn_fdot2(a, b, c, false);
#else
    return fmaf((float)a[0], (float)b[0], fmaf((float)a[1], (float)b[1], c));
#endif
}

__global__ void prep_kernel(const float* __restrict__ W0, const float* __restrict__ W1,
                            const float* __restrict__ W2, const float* __restrict__ hW,
                            _Float16* __restrict__ ws) {
    const int tid = blockIdx.x * blockDim.x + threadIdx.x;
    const int stride = gridDim.x * blockDim.x;
    _Float16* w0f = ws + W0F_OFF / 2;
    _Float16* w1f = ws + W1F_OFF / 2;
    _Float16* w2f = ws + W2F_OFF / 2;
    _Float16* hwt = ws + HWT_OFF / 2;
    // layer 0: frag (kk,g) covers k0 = kk*32+g*8, EXCEPT (2,3) which covers
    // k=81..88 with j<7 weights zeroed (those k are duplicated in frag (2,2)).
    for (int i = tid; i < 3 * 4 * 64 * 8; i += stride) {
        int j = i & 7, l = (i >> 3) & 63, fk = i >> 9;   // fk = kk*4+ft
        int kk = fk >> 2, ft = fk & 3;
        int n = ft * 16 + (l & 15);
        int g = l >> 4;
        bool tail = (kk == 2 && g == 3);
        int k = (tail ? 81 : kk * 32 + g * 8) + j;       // always <= 88
        float wv = W0[k * HID + n];
        if (tail && j < 7) wv = 0.0f;                    // duplicate k: zero weight
        w0f[i] = (_Float16)wv;
    }
    for (int i = tid; i < 2 * 4 * 64 * 8; i += stride) {
        int j = i & 7, l = (i >> 3) & 63, fk = i >> 9;
        int kk = fk >> 2, ft = fk & 3;
        int n = ft * 16 + (l & 15);
        int k = kk * 32 + (l >> 4) * 8 + j;
        w1f[i] = (_Float16)W1[k * HID + n];
        w2f[i] = (_Float16)W2[k * HID + n];
    }
    for (int i = tid; i < NTASK * OUTF * HID; i += stride) {   // hwT[t][o][k]
        int t = i / (OUTF * HID), rem = i % (OUTF * HID);
        int o = rem / HID, k = rem % HID;
        hwt[i] = (_Float16)hW[(size_t)t * (HID * OUTF) + k * OUTF + o];
    }
}

__global__ __launch_bounds__(NTHR, 4) void mtn_mfma_kernel(
    const float* __restrict__ x,     // [B, 89]
    const int*   __restrict__ task,  // [B]
    const float* __restrict__ b0, const float* __restrict__ b1,
    const float* __restrict__ b2,
    const float* __restrict__ hB,    // [50, 8] fp32
    const _Float16* __restrict__ ws,
    float* __restrict__ out)         // [B, 8]
{
    __shared__ __align__(16) _Float16 wl[WLF];          // 28672 B: W0F|W1F|W2F
    __shared__ __align__(16) _Float16 hs[NW][32][HP];   // 36864 B, wave-private bands

    const int t = threadIdx.x;
    const int w = t >> 6;            // wave 0..7
    const int l = t & 63;
    const int c = l & 15;            // MFMA col (batch) / A row (feat)
    const int g = l >> 4;            // k-group / D row-group
    const int waveRow = blockIdx.x * ROWS + w * 32;   // global row base of this wave

    const _Float16* hwt = ws + HWT_OFF / 2;

    // ---- stage ALL trunk weights to LDS: 1792 float4 = 3*512 + 256, coalesced
    {
        const float4* src = reinterpret_cast<const float4*>(ws);   // frag block @0
        float4* dst = reinterpret_cast<float4*>(wl);
        #pragma unroll
        for (int i = 0; i < 3; ++i) dst[t + i * NTHR] = src[t + i * NTHR];
        if (t < 1792 - 3 * NTHR) dst[t + 3 * NTHR] = src[t + 3 * NTHR];
    }

    // ---- layer-0 B-fragments: direct global->VGPR, branchless (overlapped tail)
    // (issued before the barrier so HBM latency overlaps the weight staging)
    const int k0_2 = (g == 3) ? 81 : 64 + g * 8;     // kk==2 chunk start
    half8 xf[3][2];
    #pragma unroll
    for (int bt = 0; bt < 2; ++bt) {
        const float* xr = x + (size_t)(waveRow + bt * 16 + c) * INF;
        #pragma unroll
        for (int kk = 0; kk < 3; ++kk) {
            const int k0 = (kk == 2) ? k0_2 : kk * 32 + g * 8;
            float v[8];
            __builtin_memcpy(v, xr + k0, 32);        // in-bounds: k0+8 <= 89
            half8 hb;
            #pragma unroll
            for (int i2 = 0; i2 < 8; ++i2) hb[i2] = (_Float16)v[i2];
            xf[kk][bt] = hb;
        }
    }

    // ---- task indices + head biases
    const int jr = l >> 3, jo = l & 7;
    int   tks[4];
    float hBv[4];
    #pragma unroll
    for (int it = 0; it < 4; ++it)
        tks[it] = task[waveRow + it * 8 + jr];
    #pragma unroll
    for (int it = 0; it < 4; ++it)
        hBv[it] = hB[tks[it] * OUTF + jo];

    __syncthreads();   // weights staged; all af reads below hit LDS

    const _Float16* w0l = wl;                 // [3kk][4ft][64][8]
    const _Float16* w1l = wl + W1F_OFF / 2;   // [2kk][4ft][64][8]
    const _Float16* w2l = wl + W2F_OFF / 2;

    f32x4 acc[4][2];   // [feat-tile][batch-tile]

    // ================= layer 0: K=96-equivalent, A frags from LDS =================
    #pragma unroll
    for (int ft = 0; ft < 4; ++ft) {
        f32x4 bv = *(const f32x4*)(b0 + ft * 16 + g * 4);
        acc[ft][0] = bv; acc[ft][1] = bv;
    }
    #pragma unroll
    for (int kk = 0; kk < 3; ++kk)
        #pragma unroll
        for (int ft = 0; ft < 4; ++ft) {
            half8 af = *(const half8*)(w0l + ((kk * 4 + ft) * 64 + l) * 8);  // ds_read_b128
            acc[ft][0] = __builtin_amdgcn_mfma_f32_16x16x32_f16(af, xf[kk][0], acc[ft][0], 0, 0, 0);
            acc[ft][1] = __builtin_amdgcn_mfma_f32_16x16x32_f16(af, xf[kk][1], acc[ft][1], 0, 0, 0);
        }
    #pragma unroll
    for (int ft = 0; ft < 4; ++ft)
        #pragma unroll
        for (int bt = 0; bt < 2; ++bt) {
            half4 hv;
            #pragma unroll
            for (int r = 0; r < 4; ++r) hv[r] = (_Float16)fast_tanh(acc[ft][bt][r]);
            *(half4*)&hs[w][bt * 16 + c][ft * 16 + g * 4] = hv;   // 8B store
        }

    // ================= layers 1,2: K=64, A and B both from LDS =============
    #pragma unroll
    for (int layer = 0; layer < 2; ++layer) {
        const _Float16* WL  = layer ? w2l : w1l;
        const float*    bia = layer ? b2  : b1;
        #pragma unroll
        for (int ft = 0; ft < 4; ++ft) {
            f32x4 bv = *(const f32x4*)(bia + ft * 16 + g * 4);
            acc[ft][0] = bv; acc[ft][1] = bv;
        }
        #pragma unroll
        for (int kk = 0; kk < 2; ++kk) {
            half8 bf[2];
            #pragma unroll
            for (int bt = 0; bt < 2; ++bt)
                bf[bt] = *(const half8*)&hs[w][bt * 16 + c][kk * 32 + g * 8];  // 16B read
            #pragma unroll
            for (int ft = 0; ft < 4; ++ft) {
                half8 af = *(const half8*)(WL + ((kk * 4 + ft) * 64 + l) * 8);
                acc[ft][0] = __builtin_amdgcn_mfma_f32_16x16x32_f16(af, bf[0], acc[ft][0], 0, 0, 0);
                acc[ft][1] = __builtin_amdgcn_mfma_f32_16x16x32_f16(af, bf[1], acc[ft][1], 0, 0, 0);
            }
        }
        #pragma unroll
        for (int ft = 0; ft < 4; ++ft)
            #pragma unroll
            for (int bt = 0; bt < 2; ++bt) {
                half4 hv;
                #pragma unroll
                for (int r = 0; r < 4; ++r) hv[r] = (_Float16)fast_tanh(acc[ft][bt][r]);
                *(half4*)&hs[w][bt * 16 + c][ft * 16 + g * 4] = hv;
            }
    }

    // ================= head: coalesced weight chunks + transpose-reduce =============
    #pragma unroll
    for (int it = 0; it < 4; ++it) {
        const int r = it * 8 + jr;
        const size_t grow = (size_t)waveRow + r;
        const int tk = tks[it];
        const _Float16* wp = hwt + (size_t)tk * (OUTF * HID) + jo * 8;  // chunk jo
        const half8 hv = *(const half8*)&hs[w][r][jo * 8];              // 1 read/it

        float p[8];
        #pragma unroll
        for (int o = 0; o < 8; ++o) {
            half8 wv = *(const half8*)(wp + o * HID);   // 8 lanes -> 128B contiguous
            float a = 0.0f;
            #pragma unroll
            for (int pp = 0; pp < 4; ++pp) {
                half2v av = {hv[2 * pp], hv[2 * pp + 1]};
                half2v bv = {wv[2 * pp], wv[2 * pp + 1]};
                a = dot2acc(av, bv, a);
            }
            p[o] = a;
        }
        // transpose-reduce across the 8 jo-lanes (static indices only)
        float t0 = p[0] + __shfl_xor(p[0], 1);
        float t1 = p[1] + __shfl_xor(p[1], 1);
        float t2 = p[2] + __shfl_xor(p[2], 1);
        float t3 = p[3] + __shfl_xor(p[3], 1);
        float t4 = p[4] + __shfl_xor(p[4], 1);
        float t5 = p[5] + __shfl_xor(p[5], 1);
        float t6 = p[6] + __shfl_xor(p[6], 1);
        float t7 = p[7] + __shfl_xor(p[7], 1);
        const bool b0s = (jo & 1) != 0;
        float s0 = b0s ? t1 : t0;
        float s1 = b0s ? t3 : t2;
        float s2 = b0s ? t5 : t4;
        float s3 = b0s ? t7 : t6;
        s0 += __shfl_xor(s0, 2);
        s1 += __shfl_xor(s1, 2);
        s2 += __shfl_xor(s2, 2);
        s3 += __shfl_xor(s3, 2);
        const bool b1s = (jo & 2) != 0;
        float u0 = b1s ? s1 : s0;
        float u1 = b1s ? s3 : s2;
        u0 += __shfl_xor(u0, 4);
        u1 += __shfl_xor(u1, 4);
        float res = ((jo & 4) ? u1 : u0) + hBv[it];
        out[grow * OUTF + jo] = res;    // wave stores 64 consecutive dwords
    }
}

extern "C" void kernel_launch(void* const* d_in, const int* in_sizes, int n_in,
                              void* d_out, int out_size, void* d_ws, size_t ws_size,
                              hipStream_t stream) {
    const float* x    = (const float*)d_in[0];
    const int*   task = (const int*)  d_in[1];
    const float* W0   = (const float*)d_in[2];
    const float* b0   = (const float*)d_in[3];
    const float* W1   = (const float*)d_in[4];
    const float* b1   = (const float*)d_in[5];
    const float* W2   = (const float*)d_in[6];
    const float* b2   = (const float*)d_in[7];
    const float* hW   = (const float*)d_in[8];
    const float* hB   = (const float*)d_in[9];
    float* out = (float*)d_out;
    _Float16* ws = (_Float16*)d_ws;

    prep_kernel<<<64, 256, 0, stream>>>(W0, W1, W2, hW, ws);
    mtn_mfma_kernel<<<BN / ROWS, NTHR, 0, stream>>>(x, task, b0, b1, b2, hB, ws, out);
}